// Round 1
// baseline (252.852 us; speedup 1.0000x reference)
//
#include <hip/hip_runtime.h>
#include <hip/hip_bf16.h>

typedef __attribute__((ext_vector_type(8))) short short8v;
typedef __attribute__((ext_vector_type(4))) float floatx4;

union Frag { uint4 u; short8v v; };

__device__ __forceinline__ unsigned int pkbf(float a, float b) {
  __hip_bfloat162 h = __float22bfloat162_rn(make_float2(a, b));
  union { __hip_bfloat162 h; unsigned int u; } c; c.h = h;
  return c.u;
}

// out[b*128+o] = bias[o]   (atomic-fallback path only)
__global__ void bias_init(const float* __restrict__ bias, float* __restrict__ out) {
  int idx = blockIdx.x * 256 + threadIdx.x;   // 32768 total
  out[idx] = bias[idx & 127];
}

// Sum 256 per-block partials + bias -> out.  grid 256 x 128.
__global__ __launch_bounds__(128)
void reduce_k(const float* __restrict__ part, const float* __restrict__ bias,
              float* __restrict__ out) {
  int o = blockIdx.x * 128 + threadIdx.x;     // 0..32767
  const float* p = part + o;
  float s0 = 0.f, s1 = 0.f, s2 = 0.f, s3 = 0.f;
  #pragma unroll 8
  for (int c = 0; c < 256; c += 4) {
    s0 += p[(long)c * 32768];
    s1 += p[(long)(c + 1) * 32768];
    s2 += p[(long)(c + 2) * 32768];
    s3 += p[(long)(c + 3) * 32768];
  }
  out[o] = s0 + s1 + s2 + s3 + bias[o & 127];
}

// ---------------------------------------------------------------------------
// Pre-pack W (fp32 [262144,128] row-major) into bf16 MFMA B-fragments.
// Fragment unit (16B = 8 bf16) for (s_abs, q, col):
//   t=0..7 : bf16( W[(s_abs*32 + q*8 + t)*128 + col] ), packed pairwise
//   u[v2] = pkbf(w[2*v2], w[2*v2+1])   -- identical packing to the old kernel.
// Stored at Wb[(s_abs*4 + q)*128 + col]  (uint4 units).
// grid 8192 (one 32-row chunk each) x 512 threads (q = tid>>7, col = tid&127).
// Reads coalesced (64 lanes x 4B consecutive cols), writes coalesced (64x16B).
// W reads nontemporal so Wb stays LLC-resident for the GEMM.
// ---------------------------------------------------------------------------
__global__ __launch_bounds__(512)
void conv_w(const float* __restrict__ W, uint4* __restrict__ Wb) {
  const int s_abs = blockIdx.x;               // 0..8191
  const int q = threadIdx.x >> 7;             // 0..3
  const int col = threadIdx.x & 127;          // 0..127
  const float* src = W + (long)(s_abs * 32 + q * 8) * 128 + col;
  float w[8];
  #pragma unroll
  for (int t = 0; t < 8; ++t)
    w[t] = __builtin_nontemporal_load(src + t * 128);
  uint4 f;
  f.x = pkbf(w[0], w[1]);
  f.y = pkbf(w[2], w[3]);
  f.z = pkbf(w[4], w[5]);
  f.w = pkbf(w[6], w[7]);
  Wb[((long)s_abs * 4 + q) * 128 + col] = f;
}

// ---------------------------------------------------------------------------
// GEMM using pre-packed bf16 W fragments: one dwordx4 load per B-fragment,
// no W-side conversion in the hot loop. Otherwise identical structure to the
// verified fp32-load kernel (same e-cache, same p_lds, same accumulators).
// ---------------------------------------------------------------------------
__global__ __launch_bounds__(512, 2)
void tfn_gemm_bf(const float* __restrict__ X, const float* __restrict__ P,
                 const float* __restrict__ Dyn, const uint4* __restrict__ Wb,
                 float* __restrict__ part) {
  __shared__ float p_lds[16][256];            // p[jj][brow]

  const int tid = threadIdx.x;
  const int wv = tid >> 6, lane = tid & 63;
  const int q = lane >> 4, l16 = lane & 15;
  const int r = wv & 3;                       // row group: rows [64r, 64r+64)
  const int cg = wv >> 2;                     // col group: cols [64cg, 64cg+64)

  const int c = blockIdx.x;
  const int i = c >> 2;
  const int j0 = (c & 3) << 4;

  // ---- stage p (16 j-values for all 256 batches) into LDS, transposed ----
  for (int idx = tid; idx < 256 * 16; idx += 512) {
    int bb = idx >> 4, jj = idx & 15;
    int j = j0 + jj;
    p_lds[jj][bb] = (j < 63) ? P[bb * 63 + j] : 1.0f;
  }

  // ---- per-lane register cache: e[rt][h][t] = a * d  (static indices only) ----
  float e[4][2][8];
  #pragma unroll
  for (int rt = 0; rt < 4; ++rt) {
    int brow = (r << 6) + (rt << 4) + l16;
    float av = (i < 63) ? X[brow * 63 + i] : 1.0f;
    #pragma unroll
    for (int h = 0; h < 2; ++h) {
      int kb = (h << 5) + (q << 3);
      #pragma unroll
      for (int t = 0; t < 8; ++t) {
        int k = kb + t;
        float dv = (k < 63) ? Dyn[brow * 63 + k] : 1.0f;
        e[rt][h][t] = av * dv;
      }
    }
  }

  floatx4 acc[4][4];
  #pragma unroll
  for (int a = 0; a < 4; ++a)
    #pragma unroll
    for (int b = 0; b < 4; ++b) acc[a][b] = (floatx4)0.0f;

  __syncthreads();   // p_lds ready; no barriers after this point

  // Fragment base for this lane: unit index (s_abs*4+q)*128 + cg*64 + nt*16 + l16
  // with s_abs = c*32 + s_rel  ->  (c*128+q)*128 + s_rel*512 + cg*64 + nt*16 + l16
  const uint4* wb = Wb + ((long)(c * 128 + q) * 128) + (cg << 6) + l16;

  Frag wA[4], wB[4];   // double-buffered B-fragments (16 VGPR each set)

  #pragma unroll
  for (int nt = 0; nt < 4; ++nt)
    wA[nt].u = wb[nt * 16];                   // s_rel = 0

  for (int jj = 0; jj < 16; ++jj) {
    float pb[4];
    #pragma unroll
    for (int rt = 0; rt < 4; ++rt)
      pb[rt] = p_lds[jj][(r << 6) + (rt << 4) + l16];

    // ---- h = 0 : compute with wA, prefetch wB (s_rel = 2jj+1) ----
    {
      #pragma unroll
      for (int nt = 0; nt < 4; ++nt)
        wB[nt].u = wb[(2 * jj + 1) * 512 + nt * 16];

      union { short8v v; unsigned int u[4]; } fa[4];
      #pragma unroll
      for (int rt = 0; rt < 4; ++rt)
        #pragma unroll
        for (int v2 = 0; v2 < 4; ++v2)
          fa[rt].u[v2] = pkbf(pb[rt] * e[rt][0][2 * v2], pb[rt] * e[rt][0][2 * v2 + 1]);
      #pragma unroll
      for (int rt = 0; rt < 4; ++rt)
        #pragma unroll
        for (int nt = 0; nt < 4; ++nt)
          acc[rt][nt] = __builtin_amdgcn_mfma_f32_16x16x32_bf16(
              fa[rt].v, wA[nt].v, acc[rt][nt], 0, 0, 0);
    }

    // ---- h = 1 : compute with wB, prefetch wA (s_rel = 2jj+2) ----
    {
      if (jj < 15) {
        #pragma unroll
        for (int nt = 0; nt < 4; ++nt)
          wA[nt].u = wb[(2 * jj + 2) * 512 + nt * 16];
      }

      union { short8v v; unsigned int u[4]; } fa[4];
      #pragma unroll
      for (int rt = 0; rt < 4; ++rt)
        #pragma unroll
        for (int v2 = 0; v2 < 4; ++v2)
          fa[rt].u[v2] = pkbf(pb[rt] * e[rt][1][2 * v2], pb[rt] * e[rt][1][2 * v2 + 1]);
      #pragma unroll
      for (int rt = 0; rt < 4; ++rt)
        #pragma unroll
        for (int nt = 0; nt < 4; ++nt)
          acc[rt][nt] = __builtin_amdgcn_mfma_f32_16x16x32_bf16(
              fa[rt].v, wB[nt].v, acc[rt][nt], 0, 0, 0);
    }
  }

  // ---- epilogue ----
  float* pt = part + ((long)c << 15);
  #pragma unroll
  for (int rt = 0; rt < 4; ++rt)
    #pragma unroll
    for (int nt = 0; nt < 4; ++nt) {
      int col = (cg << 6) + (nt << 4) + l16;
      #pragma unroll
      for (int g = 0; g < 4; ++g) {
        int brow = (r << 6) + (rt << 4) + (q << 2) + g;
        pt[brow * 128 + col] = acc[rt][nt][g];
      }
    }
}

// ---------------------------------------------------------------------------
// Fallback GEMM (previous verified kernel): fp32 W loads + in-loop conversion.
// Used when the workspace is too small for the packed-W path.
// ---------------------------------------------------------------------------
__global__ __launch_bounds__(512, 2)
void tfn_gemm(const float* __restrict__ X, const float* __restrict__ P,
              const float* __restrict__ Dyn, const float* __restrict__ W,
              float* __restrict__ part, float* __restrict__ out, int use_ws) {
  __shared__ float p_lds[16][256];            // p[jj][brow]

  const int tid = threadIdx.x;
  const int wv = tid >> 6, lane = tid & 63;
  const int q = lane >> 4, l16 = lane & 15;
  const int r = wv & 3;
  const int cg = wv >> 2;

  const int c = blockIdx.x;
  const int i = c >> 2;
  const int j0 = (c & 3) << 4;
  const long gk0 = (long)c << 10;

  for (int idx = tid; idx < 256 * 16; idx += 512) {
    int bb = idx >> 4, jj = idx & 15;
    int j = j0 + jj;
    p_lds[jj][bb] = (j < 63) ? P[bb * 63 + j] : 1.0f;
  }

  float e[4][2][8];
  #pragma unroll
  for (int rt = 0; rt < 4; ++rt) {
    int brow = (r << 6) + (rt << 4) + l16;
    float av = (i < 63) ? X[brow * 63 + i] : 1.0f;
    #pragma unroll
    for (int h = 0; h < 2; ++h) {
      int kb = (h << 5) + (q << 3);
      #pragma unroll
      for (int t = 0; t < 8; ++t) {
        int k = kb + t;
        float dv = (k < 63) ? Dyn[brow * 63 + k] : 1.0f;
        e[rt][h][t] = av * dv;
      }
    }
  }

  floatx4 acc[4][4];
  #pragma unroll
  for (int a = 0; a < 4; ++a)
    #pragma unroll
    for (int b = 0; b < 4; ++b) acc[a][b] = (floatx4)0.0f;

  __syncthreads();

  const float* wstep = W + (gk0 + (q << 3)) * 128 + (cg << 6) + l16;

  float wA[4][8], wB[4][8];

  #pragma unroll
  for (int nt = 0; nt < 4; ++nt)
    #pragma unroll
    for (int t = 0; t < 8; ++t)
      wA[nt][t] = wstep[t * 128 + nt * 16];

  for (int jj = 0; jj < 16; ++jj) {
    float pb[4];
    #pragma unroll
    for (int rt = 0; rt < 4; ++rt)
      pb[rt] = p_lds[jj][(r << 6) + (rt << 4) + l16];

    {
      const float* wp = wstep + ((long)(2 * jj + 1) << 12);
      #pragma unroll
      for (int nt = 0; nt < 4; ++nt)
        #pragma unroll
        for (int t = 0; t < 8; ++t)
          wB[nt][t] = wp[t * 128 + nt * 16];

      union { short8v v; unsigned int u[4]; } fb[4], fa[4];
      #pragma unroll
      for (int nt = 0; nt < 4; ++nt)
        #pragma unroll
        for (int v2 = 0; v2 < 4; ++v2)
          fb[nt].u[v2] = pkbf(wA[nt][2 * v2], wA[nt][2 * v2 + 1]);
      #pragma unroll
      for (int rt = 0; rt < 4; ++rt)
        #pragma unroll
        for (int v2 = 0; v2 < 4; ++v2)
          fa[rt].u[v2] = pkbf(pb[rt] * e[rt][0][2 * v2], pb[rt] * e[rt][0][2 * v2 + 1]);
      #pragma unroll
      for (int rt = 0; rt < 4; ++rt)
        #pragma unroll
        for (int nt = 0; nt < 4; ++nt)
          acc[rt][nt] = __builtin_amdgcn_mfma_f32_16x16x32_bf16(
              fa[rt].v, fb[nt].v, acc[rt][nt], 0, 0, 0);
    }

    {
      if (jj < 15) {
        const float* wp = wstep + ((long)(2 * jj + 2) << 12);
        #pragma unroll
        for (int nt = 0; nt < 4; ++nt)
          #pragma unroll
          for (int t = 0; t < 8; ++t)
            wA[nt][t] = wp[t * 128 + nt * 16];
      }

      union { short8v v; unsigned int u[4]; } fb[4], fa[4];
      #pragma unroll
      for (int nt = 0; nt < 4; ++nt)
        #pragma unroll
        for (int v2 = 0; v2 < 4; ++v2)
          fb[nt].u[v2] = pkbf(wB[nt][2 * v2], wB[nt][2 * v2 + 1]);
      #pragma unroll
      for (int rt = 0; rt < 4; ++rt)
        #pragma unroll
        for (int v2 = 0; v2 < 4; ++v2)
          fa[rt].u[v2] = pkbf(pb[rt] * e[rt][1][2 * v2], pb[rt] * e[rt][1][2 * v2 + 1]);
      #pragma unroll
      for (int rt = 0; rt < 4; ++rt)
        #pragma unroll
        for (int nt = 0; nt < 4; ++nt)
          acc[rt][nt] = __builtin_amdgcn_mfma_f32_16x16x32_bf16(
              fa[rt].v, fb[nt].v, acc[rt][nt], 0, 0, 0);
    }
  }

  if (use_ws) {
    float* pt = part + ((long)c << 15);
    #pragma unroll
    for (int rt = 0; rt < 4; ++rt)
      #pragma unroll
      for (int nt = 0; nt < 4; ++nt) {
        int col = (cg << 6) + (nt << 4) + l16;
        #pragma unroll
        for (int g = 0; g < 4; ++g) {
          int brow = (r << 6) + (rt << 4) + (q << 2) + g;
          pt[brow * 128 + col] = acc[rt][nt][g];
        }
      }
  } else {
    #pragma unroll
    for (int rt = 0; rt < 4; ++rt)
      #pragma unroll
      for (int nt = 0; nt < 4; ++nt) {
        int col = (cg << 6) + (nt << 4) + l16;
        #pragma unroll
        for (int g = 0; g < 4; ++g) {
          int brow = (r << 6) + (rt << 4) + (q << 2) + g;
          atomicAdd(&out[brow * 128 + col], acc[rt][nt][g]);
        }
      }
  }
}

extern "C" void kernel_launch(void* const* d_in, const int* in_sizes, int n_in,
                              void* d_out, int out_size, void* d_ws, size_t ws_size,
                              hipStream_t stream) {
  const float* x   = (const float*)d_in[0];
  const float* p   = (const float*)d_in[1];
  const float* dyn = (const float*)d_in[2];
  const float* W   = (const float*)d_in[3];
  const float* b   = (const float*)d_in[4];
  float* out = (float*)d_out;

  const size_t wb_bytes   = (size_t)262144 * 128 * 2;          // 64 MiB packed bf16 W
  const size_t part_bytes = (size_t)256 * 32768 * sizeof(float); // 32 MiB partials
  const size_t need_new   = wb_bytes + part_bytes;               // 96 MiB
  const size_t need_old   = part_bytes;

  if (d_ws != nullptr && ws_size >= need_new) {
    uint4* Wb   = (uint4*)d_ws;
    float* part = (float*)((char*)d_ws + wb_bytes);
    conv_w<<<8192, 512, 0, stream>>>(W, Wb);
    tfn_gemm_bf<<<256, 512, 0, stream>>>(x, p, dyn, Wb, part);
    reduce_k<<<256, 128, 0, stream>>>(part, b, out);
  } else if (d_ws != nullptr && ws_size >= need_old) {
    float* part = (float*)d_ws;
    tfn_gemm<<<256, 512, 0, stream>>>(x, p, dyn, W, part, out, 1);
    reduce_k<<<256, 128, 0, stream>>>(part, b, out);
  } else {
    bias_init<<<128, 256, 0, stream>>>(b, out);
    tfn_gemm<<<256, 512, 0, stream>>>(x, p, dyn, W, nullptr, out, 0);
  }
}

// Round 3
// 226.490 us; speedup vs baseline: 1.1164x; 1.1164x over previous
//
#include <hip/hip_runtime.h>
#include <hip/hip_bf16.h>

typedef __attribute__((ext_vector_type(8))) short short8v;
typedef __attribute__((ext_vector_type(4))) float floatx4;
typedef __attribute__((ext_vector_type(4))) unsigned int uint4v;

__device__ __forceinline__ unsigned int pkbf(float a, float b) {
  __hip_bfloat162 h = __float22bfloat162_rn(make_float2(a, b));
  union { __hip_bfloat162 h; unsigned int u; } c; c.h = h;
  return c.u;
}

// out[b*128+o] = bias[o]   (atomic-fallback path only)
__global__ void bias_init(const float* __restrict__ bias, float* __restrict__ out) {
  int idx = blockIdx.x * 256 + threadIdx.x;   // 32768 total
  out[idx] = bias[idx & 127];
}

// ---------------------------------------------------------------------------
// reduce: out[o] = bias[o&127] + sum_c part[c*32768 + o]
// 256 blocks x 512 threads; block handles 128 outputs, 4-way c-split per
// thread (64 partials each), LDS combine. 8 waves/CU; coalesced strided loads.
// ---------------------------------------------------------------------------
__global__ __launch_bounds__(512)
void reduce_v3(const float* __restrict__ part, const float* __restrict__ bias,
               float* __restrict__ out) {
  const int tid = threadIdx.x;
  const int o = tid & 127;                    // output within block's 128-range
  const int qr = tid >> 7;                    // c-quarter 0..3
  const int og = blockIdx.x * 128 + o;        // global output index 0..32767

  const float* pp = part + (((long)(qr * 64)) << 15) + og;
  float s0 = 0.f, s1 = 0.f, s2 = 0.f, s3 = 0.f;
  #pragma unroll 4
  for (int n = 0; n < 64; n += 4) {
    s0 += __builtin_nontemporal_load(pp + ((long)n << 15));
    s1 += __builtin_nontemporal_load(pp + ((long)(n + 1) << 15));
    s2 += __builtin_nontemporal_load(pp + ((long)(n + 2) << 15));
    s3 += __builtin_nontemporal_load(pp + ((long)(n + 3) << 15));
  }
  float sum = (s0 + s1) + (s2 + s3);

  __shared__ float red[3][128];
  if (qr) red[qr - 1][o] = sum;
  __syncthreads();
  if (qr == 0)
    out[og] = sum + red[0][o] + red[1][o] + red[2][o] + bias[o];
}

// ---------------------------------------------------------------------------
// GEMM v3: partial_c[256,128] = F[256, Kchunk_c] @ W[Kchunk_c, 128]
// F[b, gk] = a[b,i]*p[b,j]*d[b,k],  gk = (i*64+j)*64+k
// block c: i = c>>2, j in [(c&3)*16, +16), k in [0,64).
// W is read fp32 DIRECTLY (no pre-pack pass): per 32-row K-step, a 16 KB
// tile is reg-staged (2 coalesced nontemporal dwordx4 per thread, issued one
// step ahead so HBM latency hides under compute) then ds_write_b128 into a
// padded LDS tile. Pad = 16 B per 1 KB (2-row) pair so the stride-512B
// fragment ds_read_b32s are 2-way bank-aliased (free, m136). bf16 conversion
// happens in-register after the LDS read — numerics identical to the
// verified packed-W kernel (same pkbf of same fp32 values, same MFMA order).
// ---------------------------------------------------------------------------
__global__ __launch_bounds__(512, 2)
void tfn_gemm_v3(const float* __restrict__ X, const float* __restrict__ P,
                 const float* __restrict__ Dyn, const float* __restrict__ W,
                 float* __restrict__ part) {
  // padded W tile: 4096 floats + 16 pairs * 4 floats pad = 4160 floats (16640 B)
  __shared__ __align__(16) float wt0[4160];
  __shared__ __align__(16) float wt1[4160];
  __shared__ float p_lds[16][256];            // p[jj][brow]

  const int tid = threadIdx.x;
  const int wv = tid >> 6, lane = tid & 63;
  const int q = lane >> 4, l16 = lane & 15;
  const int r = wv & 3;                       // row group: rows [64r, 64r+64)
  const int cg = wv >> 2;                     // col group: cols [64cg, 64cg+64)

  const int c = blockIdx.x;
  const int i = c >> 2;
  const int j0 = (c & 3) << 4;

  // tile s = 32 W-rows starting at (c*1024 + s*32); 16 KB = 1024 uint4
  const uint4v* wsrc = (const uint4v*)(W + (((long)c) << 10) * 128);

  // ---- prologue: issue tile-0 loads immediately (cover latency w/ staging) --
  uint4v rg0 = __builtin_nontemporal_load(&wsrc[tid]);
  uint4v rg1 = __builtin_nontemporal_load(&wsrc[512 + tid]);

  // ---- stage p (16 j-values for all 256 batches) into LDS, transposed ----
  for (int idx = tid; idx < 256 * 16; idx += 512) {
    int bb = idx >> 4, jj = idx & 15;
    int j = j0 + jj;
    p_lds[jj][bb] = (j < 63) ? P[bb * 63 + j] : 1.0f;
  }

  // ---- per-lane register cache: e[rt][h][t] = a * d ----
  float e[4][2][8];
  #pragma unroll
  for (int rt = 0; rt < 4; ++rt) {
    int brow = (r << 6) + (rt << 4) + l16;
    float av = (i < 63) ? X[brow * 63 + i] : 1.0f;
    #pragma unroll
    for (int h = 0; h < 2; ++h) {
      int kb = (h << 5) + (q << 3);
      #pragma unroll
      for (int t = 0; t < 8; ++t) {
        int k = kb + t;
        float dv = (k < 63) ? Dyn[brow * 63 + k] : 1.0f;
        e[rt][h][t] = av * dv;
      }
    }
  }

  // padded LDS write destinations (thread writes 16B at linear L, L+8KB)
  const int Lf0 = tid << 2;                   // float-linear offset, chunk 0
  const int Lf1 = (tid + 512) << 2;           // chunk 1
  const int d0 = Lf0 + ((Lf0 >> 8) << 2);     // +4 floats pad per 256-float pair
  const int d1 = Lf1 + ((Lf1 >> 8) << 2);

  // ---- write tile 0 into wt0, then issue tile-1 loads ----
  *(uint4v*)&wt0[d0] = rg0;
  *(uint4v*)&wt0[d1] = rg1;
  rg0 = __builtin_nontemporal_load(&wsrc[1024 + tid]);
  rg1 = __builtin_nontemporal_load(&wsrc[1536 + tid]);

  floatx4 acc[4][4];
  #pragma unroll
  for (int a = 0; a < 4; ++a)
    #pragma unroll
    for (int b = 0; b < 4; ++b) acc[a][b] = (floatx4)0.0f;

  // fragment read base: element (krow=q*8+t, col) at
  //   krow*128 + (krow>>1)*4 + col  =  q*1040 + col_base  +  t*128 + (t>>1)*4
  const int wbase = q * 1040 + (cg << 6) + l16;
  const int prow = (r << 6) + l16;

  __syncthreads();   // p_lds + tile 0 visible

  for (int jj = 0; jj < 16; ++jj) {
    float pb[4];
    #pragma unroll
    for (int rt = 0; rt < 4; ++rt)
      pb[rt] = p_lds[jj][prow + (rt << 4)];

    // ---- s = 2jj (even): compute from wt0; write tile s+1 -> wt1; load s+2 --
    {
      *(uint4v*)&wt1[d0] = rg0;               // tile 2jj+1 (regs from prev step)
      *(uint4v*)&wt1[d1] = rg1;
      if (jj < 15) {
        rg0 = __builtin_nontemporal_load(&wsrc[(2 * jj + 2) * 1024 + tid]);
        rg1 = __builtin_nontemporal_load(&wsrc[(2 * jj + 2) * 1024 + 512 + tid]);
      }

      float w[4][8];
      #pragma unroll
      for (int nt = 0; nt < 4; ++nt)
        #pragma unroll
        for (int t = 0; t < 8; ++t)
          w[nt][t] = wt0[wbase + (nt << 4) + t * 128 + ((t >> 1) << 2)];

      union { short8v v; unsigned int u[4]; } fb[4], fa[4];
      #pragma unroll
      for (int nt = 0; nt < 4; ++nt)
        #pragma unroll
        for (int v2 = 0; v2 < 4; ++v2)
          fb[nt].u[v2] = pkbf(w[nt][2 * v2], w[nt][2 * v2 + 1]);
      #pragma unroll
      for (int rt = 0; rt < 4; ++rt)
        #pragma unroll
        for (int v2 = 0; v2 < 4; ++v2)
          fa[rt].u[v2] = pkbf(pb[rt] * e[rt][0][2 * v2], pb[rt] * e[rt][0][2 * v2 + 1]);
      #pragma unroll
      for (int rt = 0; rt < 4; ++rt)
        #pragma unroll
        for (int nt = 0; nt < 4; ++nt)
          acc[rt][nt] = __builtin_amdgcn_mfma_f32_16x16x32_bf16(
              fa[rt].v, fb[nt].v, acc[rt][nt], 0, 0, 0);

      __syncthreads();
    }

    // ---- s = 2jj+1 (odd): compute from wt1; write tile s+1 -> wt0; load s+2 --
    {
      if (jj < 15) {
        *(uint4v*)&wt0[d0] = rg0;             // tile 2jj+2
        *(uint4v*)&wt0[d1] = rg1;
        rg0 = __builtin_nontemporal_load(&wsrc[(2 * jj + 3) * 1024 + tid]);
        rg1 = __builtin_nontemporal_load(&wsrc[(2 * jj + 3) * 1024 + 512 + tid]);
      }

      float w[4][8];
      #pragma unroll
      for (int nt = 0; nt < 4; ++nt)
        #pragma unroll
        for (int t = 0; t < 8; ++t)
          w[nt][t] = wt1[wbase + (nt << 4) + t * 128 + ((t >> 1) << 2)];

      union { short8v v; unsigned int u[4]; } fb[4], fa[4];
      #pragma unroll
      for (int nt = 0; nt < 4; ++nt)
        #pragma unroll
        for (int v2 = 0; v2 < 4; ++v2)
          fb[nt].u[v2] = pkbf(w[nt][2 * v2], w[nt][2 * v2 + 1]);
      #pragma unroll
      for (int rt = 0; rt < 4; ++rt)
        #pragma unroll
        for (int v2 = 0; v2 < 4; ++v2)
          fa[rt].u[v2] = pkbf(pb[rt] * e[rt][1][2 * v2], pb[rt] * e[rt][1][2 * v2 + 1]);
      #pragma unroll
      for (int rt = 0; rt < 4; ++rt)
        #pragma unroll
        for (int nt = 0; nt < 4; ++nt)
          acc[rt][nt] = __builtin_amdgcn_mfma_f32_16x16x32_bf16(
              fa[rt].v, fb[nt].v, acc[rt][nt], 0, 0, 0);

      if (jj < 15) __syncthreads();
    }
  }

  // ---- epilogue: store partial [256,128] ----
  float* pt = part + ((long)c << 15);
  #pragma unroll
  for (int rt = 0; rt < 4; ++rt)
    #pragma unroll
    for (int nt = 0; nt < 4; ++nt) {
      int col = (cg << 6) + (nt << 4) + l16;
      #pragma unroll
      for (int g = 0; g < 4; ++g) {
        int brow = (r << 6) + (rt << 4) + (q << 2) + g;
        pt[brow * 128 + col] = acc[rt][nt][g];
      }
    }
}

// ---------------------------------------------------------------------------
// Fallback GEMM (verified old kernel): fp32 scalar W loads + atomics.
// Used only when no workspace is available.
// ---------------------------------------------------------------------------
__global__ __launch_bounds__(512, 2)
void tfn_gemm(const float* __restrict__ X, const float* __restrict__ P,
              const float* __restrict__ Dyn, const float* __restrict__ W,
              float* __restrict__ out) {
  __shared__ float p_lds[16][256];

  const int tid = threadIdx.x;
  const int wv = tid >> 6, lane = tid & 63;
  const int q = lane >> 4, l16 = lane & 15;
  const int r = wv & 3;
  const int cg = wv >> 2;

  const int c = blockIdx.x;
  const int i = c >> 2;
  const int j0 = (c & 3) << 4;
  const long gk0 = (long)c << 10;

  for (int idx = tid; idx < 256 * 16; idx += 512) {
    int bb = idx >> 4, jj = idx & 15;
    int j = j0 + jj;
    p_lds[jj][bb] = (j < 63) ? P[bb * 63 + j] : 1.0f;
  }

  float e[4][2][8];
  #pragma unroll
  for (int rt = 0; rt < 4; ++rt) {
    int brow = (r << 6) + (rt << 4) + l16;
    float av = (i < 63) ? X[brow * 63 + i] : 1.0f;
    #pragma unroll
    for (int h = 0; h < 2; ++h) {
      int kb = (h << 5) + (q << 3);
      #pragma unroll
      for (int t = 0; t < 8; ++t) {
        int k = kb + t;
        float dv = (k < 63) ? Dyn[brow * 63 + k] : 1.0f;
        e[rt][h][t] = av * dv;
      }
    }
  }

  floatx4 acc[4][4];
  #pragma unroll
  for (int a = 0; a < 4; ++a)
    #pragma unroll
    for (int b = 0; b < 4; ++b) acc[a][b] = (floatx4)0.0f;

  __syncthreads();

  const float* wstep = W + (gk0 + (q << 3)) * 128 + (cg << 6) + l16;

  float wA[4][8], wB[4][8];
  #pragma unroll
  for (int nt = 0; nt < 4; ++nt)
    #pragma unroll
    for (int t = 0; t < 8; ++t)
      wA[nt][t] = wstep[t * 128 + nt * 16];

  for (int jj = 0; jj < 16; ++jj) {
    float pb[4];
    #pragma unroll
    for (int rt = 0; rt < 4; ++rt)
      pb[rt] = p_lds[jj][(r << 6) + (rt << 4) + l16];

    {
      const float* wp = wstep + ((long)(2 * jj + 1) << 12);
      #pragma unroll
      for (int nt = 0; nt < 4; ++nt)
        #pragma unroll
        for (int t = 0; t < 8; ++t)
          wB[nt][t] = wp[t * 128 + nt * 16];

      union { short8v v; unsigned int u[4]; } fb[4], fa[4];
      #pragma unroll
      for (int nt = 0; nt < 4; ++nt)
        #pragma unroll
        for (int v2 = 0; v2 < 4; ++v2)
          fb[nt].u[v2] = pkbf(wA[nt][2 * v2], wA[nt][2 * v2 + 1]);
      #pragma unroll
      for (int rt = 0; rt < 4; ++rt)
        #pragma unroll
        for (int v2 = 0; v2 < 4; ++v2)
          fa[rt].u[v2] = pkbf(pb[rt] * e[rt][0][2 * v2], pb[rt] * e[rt][0][2 * v2 + 1]);
      #pragma unroll
      for (int rt = 0; rt < 4; ++rt)
        #pragma unroll
        for (int nt = 0; nt < 4; ++nt)
          acc[rt][nt] = __builtin_amdgcn_mfma_f32_16x16x32_bf16(
              fa[rt].v, fb[nt].v, acc[rt][nt], 0, 0, 0);
    }

    {
      if (jj < 15) {
        const float* wp = wstep + ((long)(2 * jj + 2) << 12);
        #pragma unroll
        for (int nt = 0; nt < 4; ++nt)
          #pragma unroll
          for (int t = 0; t < 8; ++t)
            wA[nt][t] = wp[t * 128 + nt * 16];
      }

      union { short8v v; unsigned int u[4]; } fb[4], fa[4];
      #pragma unroll
      for (int nt = 0; nt < 4; ++nt)
        #pragma unroll
        for (int v2 = 0; v2 < 4; ++v2)
          fb[nt].u[v2] = pkbf(wB[nt][2 * v2], wB[nt][2 * v2 + 1]);
      #pragma unroll
      for (int rt = 0; rt < 4; ++rt)
        #pragma unroll
        for (int v2 = 0; v2 < 4; ++v2)
          fa[rt].u[v2] = pkbf(pb[rt] * e[rt][1][2 * v2], pb[rt] * e[rt][1][2 * v2 + 1]);
      #pragma unroll
      for (int rt = 0; rt < 4; ++rt)
        #pragma unroll
        for (int nt = 0; nt < 4; ++nt)
          acc[rt][nt] = __builtin_amdgcn_mfma_f32_16x16x32_bf16(
              fa[rt].v, fb[nt].v, acc[rt][nt], 0, 0, 0);
    }
  }

  #pragma unroll
  for (int rt = 0; rt < 4; ++rt)
    #pragma unroll
    for (int nt = 0; nt < 4; ++nt) {
      int col = (cg << 6) + (nt << 4) + l16;
      #pragma unroll
      for (int g = 0; g < 4; ++g) {
        int brow = (r << 6) + (rt << 4) + (q << 2) + g;
        atomicAdd(&out[brow * 128 + col], acc[rt][nt][g]);
      }
    }
}

extern "C" void kernel_launch(void* const* d_in, const int* in_sizes, int n_in,
                              void* d_out, int out_size, void* d_ws, size_t ws_size,
                              hipStream_t stream) {
  const float* x   = (const float*)d_in[0];
  const float* p   = (const float*)d_in[1];
  const float* dyn = (const float*)d_in[2];
  const float* W   = (const float*)d_in[3];
  const float* b   = (const float*)d_in[4];
  float* out = (float*)d_out;

  const size_t part_bytes = (size_t)256 * 32768 * sizeof(float); // 32 MiB partials

  if (d_ws != nullptr && ws_size >= part_bytes) {
    float* part = (float*)d_ws;
    tfn_gemm_v3<<<256, 512, 0, stream>>>(x, p, dyn, W, part);
    reduce_v3<<<256, 512, 0, stream>>>(part, b, out);
  } else {
    bias_init<<<128, 256, 0, stream>>>(b, out);
    tfn_gemm<<<256, 512, 0, stream>>>(x, p, dyn, W, out);
  }
}